// Round 1
// baseline (52.101 us; speedup 1.0000x reference)
//
#include <hip/hip_runtime.h>

// QFCModel: avg-pool 6x6 -> 16 angles -> 4-qubit circuit -> <Z> -> log_softmax
// One thread = one image for the circuit; block of 256 threads stages 8-image
// chunks into LDS with coalesced float4 loads (double-buffered) and pools there.

#define CH 8            // images staged per chunk
#define PADF 584        // LDS float stride per image (576 + 8 pad, spreads banks)
#define XPS 257         // xp[16][XPS] transposed angle buffer (conflict-free reads)
#define NCHUNK 32       // 256 images / 8

__device__ __forceinline__ void cmul(float ar, float ai, float br, float bi,
                                     float& cr, float& ci) {
  cr = ar * br - ai * bi;
  ci = ar * bi + ai * br;
}

struct C2 { float r0, i0, r1, i1; };   // complex 2-vector (wire state)

__device__ __forceinline__ void g_rx(C2& v, float h) {  // h = theta/2
  float s, c; __sincosf(h, &s, &c);
  C2 n;
  n.r0 = c * v.r0 + s * v.i1;
  n.i0 = c * v.i0 - s * v.r1;
  n.r1 = c * v.r1 + s * v.i0;
  n.i1 = c * v.i1 - s * v.r0;
  v = n;
}
__device__ __forceinline__ void g_ry(C2& v, float h) {
  float s, c; __sincosf(h, &s, &c);
  C2 n;
  n.r0 = c * v.r0 - s * v.r1;
  n.i0 = c * v.i0 - s * v.i1;
  n.r1 = s * v.r0 + c * v.r1;
  n.i1 = s * v.i0 + c * v.i1;
  v = n;
}
__device__ __forceinline__ void g_rz(C2& v, float h) {
  float s, c; __sincosf(h, &s, &c);
  C2 n;
  n.r0 = c * v.r0 + s * v.i0;
  n.i0 = c * v.i0 - s * v.r0;
  n.r1 = c * v.r1 - s * v.i1;
  n.i1 = c * v.i1 + s * v.r1;
  v = n;
}

__global__ __launch_bounds__(256, 2)
void qfc_kernel(const float* __restrict__ x,
                const float* __restrict__ thrx,
                const float* __restrict__ thry,
                const float* __restrict__ thrz,
                const float* __restrict__ thcrx,
                float* __restrict__ out) {
  __shared__ float stage[2][CH * PADF];
  __shared__ float xp[16][XPS];

  const int t = threadIdx.x;
  const long long img0 = (long long)blockIdx.x * 256;
  const float4* __restrict__ x4 = reinterpret_cast<const float4*>(x);

  float4 s0, s1, s2, s3, s4;  // staging regs (chunk = 1152 float4 = 4.5/thread)

  auto load_chunk = [&](int c) {
    long long base = (img0 + (long long)c * CH) * 144;  // float4 units
    s0 = x4[base + (0 * 256 + t)];
    s1 = x4[base + (1 * 256 + t)];
    s2 = x4[base + (2 * 256 + t)];
    s3 = x4[base + (3 * 256 + t)];
    if (t < 128) s4 = x4[base + (4 * 256 + t)];
  };
  auto write_chunk = [&](int buf) {
    float* sp = stage[buf];
    auto wr = [&](int idx, float4 v) {
      int img = idx / 144;
      int off4 = idx - img * 144;
      *reinterpret_cast<float4*>(&sp[img * PADF + off4 * 4]) = v;
    };
    wr(0 * 256 + t, s0);
    wr(1 * 256 + t, s1);
    wr(2 * 256 + t, s2);
    wr(3 * 256 + t, s3);
    if (t < 128) wr(4 * 256 + t, s4);
  };

  // ---------------- pooling pipeline ----------------
  load_chunk(0);
  write_chunk(0);
  __syncthreads();

  for (int c = 0; c < NCHUNK; ++c) {
    if (c + 1 < NCHUNK) load_chunk(c + 1);  // issue next loads early (overlap)
    if (t < CH * 16) {                      // 128 pool outputs this chunk
      int img = t >> 4;                     // 0..7 within chunk
      int pool = t & 15;                    // r0*4 + c0
      int r0 = pool >> 2, c0 = pool & 3;
      const float* b = &stage[c & 1][img * PADF + r0 * 144 + c0 * 6];
      float sum = 0.f;
#pragma unroll
      for (int r = 0; r < 6; ++r) {
        float2 a0 = *reinterpret_cast<const float2*>(b + r * 24);
        float2 a1 = *reinterpret_cast<const float2*>(b + r * 24 + 2);
        float2 a2 = *reinterpret_cast<const float2*>(b + r * 24 + 4);
        sum += a0.x + a0.y + a1.x + a1.y + a2.x + a2.y;
      }
      xp[pool][c * CH + img] = sum * (1.0f / 36.0f);
    }
    __syncthreads();
    if (c + 1 < NCHUNK) write_chunk((c + 1) & 1);
    __syncthreads();
  }

  // ---------------- circuit: one thread = one image ----------------
  float a[16];
#pragma unroll
  for (int j = 0; j < 16; ++j) a[j] = xp[j][t];  // conflict-free (stride 257)

  const float arx = thrx[0] * 0.5f;
  const float ary = thry[0] * 0.5f;
  const float arz = thrz[0] * 0.5f;
  const float acr = thcrx[0] * 0.5f;

  // product state: all 1q gates (encoder + trainable RX0/RY1/RZ3) fold per-wire
  C2 v[4];
#pragma unroll
  for (int w = 0; w < 4; ++w) {
    v[w].r0 = 1.f; v[w].i0 = 0.f; v[w].r1 = 0.f; v[w].i1 = 0.f;
    g_rx(v[w], a[w] * 0.5f);
    g_ry(v[w], a[4 + w] * 0.5f);
    g_rz(v[w], a[8 + w] * 0.5f);
    g_rx(v[w], a[12 + w] * 0.5f);
  }
  g_rx(v[0], arx);
  g_ry(v[1], ary);
  g_rz(v[3], arz);

  float t01r[4], t01i[4], t23r[4], t23i[4];
  cmul(v[0].r0, v[0].i0, v[1].r0, v[1].i0, t01r[0], t01i[0]);
  cmul(v[0].r0, v[0].i0, v[1].r1, v[1].i1, t01r[1], t01i[1]);
  cmul(v[0].r1, v[0].i1, v[1].r0, v[1].i0, t01r[2], t01i[2]);
  cmul(v[0].r1, v[0].i1, v[1].r1, v[1].i1, t01r[3], t01i[3]);
  cmul(v[2].r0, v[2].i0, v[3].r0, v[3].i0, t23r[0], t23i[0]);
  cmul(v[2].r0, v[2].i0, v[3].r1, v[3].i1, t23r[1], t23i[1]);
  cmul(v[2].r1, v[2].i1, v[3].r0, v[3].i0, t23r[2], t23i[2]);
  cmul(v[2].r1, v[2].i1, v[3].r1, v[3].i1, t23r[3], t23i[3]);

  float re[16], im[16];   // idx = w0*8 + w1*4 + w2*2 + w3
#pragma unroll
  for (int hi = 0; hi < 4; ++hi)
#pragma unroll
    for (int lo = 0; lo < 4; ++lo)
      cmul(t01r[hi], t01i[hi], t23r[lo], t23i[lo], re[hi * 4 + lo], im[hi * 4 + lo]);

  // CRX(theta_crx) control wire0, target wire2: RX on pairs (i,i+2), i in {8,9,12,13}
  {
    float s, cc; __sincosf(acr, &s, &cc);
#pragma unroll
    for (int k = 0; k < 4; ++k) {
      const int pi4[4] = {8, 9, 12, 13};
      int i = pi4[k], j = i + 2;
      float nir = cc * re[i] + s * im[j];
      float nii = cc * im[i] - s * re[j];
      float njr = cc * re[j] + s * im[i];
      float nji = cc * im[j] - s * re[i];
      re[i] = nir; im[i] = nii; re[j] = njr; im[j] = nji;
    }
  }
  // H on wire 3: pairs (2k, 2k+1)
#pragma unroll
  for (int i = 0; i < 16; i += 2) {
    const float inv = 0.70710678118654752f;
    float ar = re[i], ai = im[i], br = re[i + 1], bi = im[i + 1];
    re[i] = (ar + br) * inv;     im[i] = (ai + bi) * inv;
    re[i + 1] = (ar - br) * inv; im[i + 1] = (ai - bi) * inv;
  }
  // SX on wire 2: pairs (i, i+2) for i with bit1(w2)==0
#pragma unroll
  for (int i = 0; i < 16; ++i) {
    if ((i & 2) == 0) {
      int j = i + 2;
      float ar = re[i], ai = im[i], br = re[j], bi = im[j];
      re[i] = 0.5f * (ar - ai + br + bi);
      im[i] = 0.5f * (ar + ai - br + bi);
      re[j] = 0.5f * (ar + ai + br - bi);
      im[j] = 0.5f * (ai - ar + br + bi);
    }
  }
  // CNOT control wire3, target wire0: swap (i, i+8) for odd i < 8
#pragma unroll
  for (int i = 1; i < 8; i += 2) {
    float tr = re[i], ti = im[i];
    re[i] = re[i + 8]; im[i] = im[i + 8];
    re[i + 8] = tr;    im[i + 8] = ti;
  }
  // U12 on wires (1,2): for w1=1,w2=0 (i in {4,5,12,13}): top=i*bot, bot=-i*top
#pragma unroll
  for (int k = 0; k < 4; ++k) {
    const int ii4[4] = {4, 5, 12, 13};
    int i = ii4[k], j = i + 2;
    float tr = re[i], ti = im[i];
    re[i] = -im[j]; im[i] = re[j];
    re[j] = ti;     im[j] = -tr;
  }

  // <Z_w> and log_softmax over 2 logits
  float z0 = 0.f, z1 = 0.f, z2 = 0.f, z3 = 0.f;
#pragma unroll
  for (int i = 0; i < 16; ++i) {
    float p = re[i] * re[i] + im[i] * im[i];
    z0 += (i & 8) ? -p : p;
    z1 += (i & 4) ? -p : p;
    z2 += (i & 2) ? -p : p;
    z3 += (i & 1) ? -p : p;
  }
  float l0 = z0 + z1, l1 = z2 + z3;
  float m = fmaxf(l0, l1);
  float e0 = __expf(l0 - m), e1 = __expf(l1 - m);
  float lse = __logf(e0 + e1);
  float2 o;
  o.x = l0 - m - lse;
  o.y = l1 - m - lse;
  reinterpret_cast<float2*>(out)[img0 + t] = o;
}

extern "C" void kernel_launch(void* const* d_in, const int* in_sizes, int n_in,
                              void* d_out, int out_size, void* d_ws, size_t ws_size,
                              hipStream_t stream) {
  const float* x = (const float*)d_in[0];
  const float* thrx = (const float*)d_in[1];
  const float* thry = (const float*)d_in[2];
  const float* thrz = (const float*)d_in[3];
  const float* thcrx = (const float*)d_in[4];
  float* out = (float*)d_out;
  // 131072 images / 256 per block = 512 blocks
  qfc_kernel<<<512, 256, 0, stream>>>(x, thrx, thry, thrz, thcrx, out);
}